// Round 15
// baseline (212.026 us; speedup 1.0000x reference)
//
#include <hip/hip_runtime.h>
#include <hip/hip_bf16.h>

#define Bq 4
#define Sq 2048
#define Dq 512
#define Hq 8
#define HDq 64
#define NCHUNK 32

typedef __attribute__((ext_vector_type(8))) short short8;
typedef __attribute__((ext_vector_type(4))) float f32x4;

#if __has_builtin(__builtin_amdgcn_exp2f)
#define EXP2(x) __builtin_amdgcn_exp2f(x)
#else
#define EXP2(x) exp2f(x)
#endif

// softmax scale folded into Q projection: q_stored = q * 0.125 * log2(e)
#define SCALE2 (0.125f * 1.44269504088896340736f)
#define INV_SCALE2 (5.545177444479562f)

__device__ __forceinline__ short bfs(float x) {
    __hip_bfloat16 h = __float2bfloat16(x);
    short r;
    __builtin_memcpy(&r, &h, 2);
    return r;
}

__device__ __forceinline__ short8 cvt8(float4 a, float4 b) {
    union { __hip_bfloat16 h[8]; short8 s; } u;
    u.h[0] = __float2bfloat16(a.x); u.h[1] = __float2bfloat16(a.y);
    u.h[2] = __float2bfloat16(a.z); u.h[3] = __float2bfloat16(a.w);
    u.h[4] = __float2bfloat16(b.x); u.h[5] = __float2bfloat16(b.y);
    u.h[6] = __float2bfloat16(b.z); u.h[7] = __float2bfloat16(b.w);
    return u.s;
}

// direct global->LDS async copy, 16B per lane (LDS dest = wave-uniform base + lane*16)
__device__ __forceinline__ void gload16(const void* g, void* l) {
    __builtin_amdgcn_global_load_lds(
        (const __attribute__((address_space(1))) unsigned int*)g,
        (__attribute__((address_space(3))) unsigned int*)l, 16, 0, 0);
}

// ---------------- batched MFMA projection: O = (X @ W^T + bias) * sc, bf16 head layout ----------------
__global__ __launch_bounds__(256, 3)
void proj_kernel(const float* __restrict__ Xv, const float* __restrict__ Xk, const float* __restrict__ Xq,
                 const float* __restrict__ Wv, const float* __restrict__ Wk, const float* __restrict__ Wq,
                 const float* __restrict__ bv, const float* __restrict__ bk, const float* __restrict__ bq,
                 __hip_bfloat16* __restrict__ Ov, __hip_bfloat16* __restrict__ Ok, __hip_bfloat16* __restrict__ Oq) {
    __shared__ alignas(16) short As[128 * 64];
    __shared__ alignas(16) short Bs[128 * 64];

    const int z = blockIdx.z;
    const float* X   = (z == 0) ? Xv : (z == 1) ? Xk : Xq;
    const float* W   = (z == 0) ? Wv : (z == 1) ? Wk : Wq;
    const float* bia = (z == 0) ? bv : (z == 1) ? bk : bq;
    __hip_bfloat16* O = (z == 0) ? Ov : (z == 1) ? Ok : Oq;
    const float sc = (z == 2) ? SCALE2 : 1.0f;

    const int tid  = threadIdx.x;
    const int lane = tid & 63;
    const int w    = tid >> 6;
    const int wr   = w >> 1;
    const int wc   = w & 1;
    const int m0   = blockIdx.y * 128;
    const int n0   = blockIdx.x * 128;
    const int arow = lane & 15;
    const int ag   = lane >> 4;

    f32x4 acc[4][4];
    #pragma unroll
    for (int t = 0; t < 4; ++t)
        #pragma unroll
        for (int u = 0; u < 4; ++u) acc[t][u] = (f32x4){0.f, 0.f, 0.f, 0.f};

    for (int kk = 0; kk < Dq / 64; ++kk) {
        __syncthreads();
        #pragma unroll
        for (int p = 0; p < 4; ++p) {
            int id  = p * 256 + tid;
            int row = id >> 3;
            int c   = id & 7;
            int dst = row * 128 + ((c * 16) ^ ((row & 7) << 4));
            const float* ax = X + (size_t)(m0 + row) * Dq + kk * 64 + c * 8;
            const float* bx = W + (size_t)(n0 + row) * Dq + kk * 64 + c * 8;
            float4 a0 = *(const float4*)ax;
            float4 a1 = *(const float4*)(ax + 4);
            float4 b0 = *(const float4*)bx;
            float4 b1 = *(const float4*)(bx + 4);
            *(short8*)((char*)As + dst) = cvt8(a0, a1);
            *(short8*)((char*)Bs + dst) = cvt8(b0, b1);
        }
        __syncthreads();
        #pragma unroll
        for (int h = 0; h < 2; ++h) {
            short8 af[4], bf[4];
            #pragma unroll
            for (int t = 0; t < 4; ++t) {
                int ra = wr * 64 + t * 16 + arow;
                int rb = wc * 64 + t * 16 + arow;
                af[t] = *(const short8*)((const char*)As + ra * 128 + ((h * 64 + ag * 16) ^ ((ra & 7) << 4)));
                bf[t] = *(const short8*)((const char*)Bs + rb * 128 + ((h * 64 + ag * 16) ^ ((rb & 7) << 4)));
            }
            #pragma unroll
            for (int t = 0; t < 4; ++t)
                #pragma unroll
                for (int u = 0; u < 4; ++u)
                    acc[t][u] = __builtin_amdgcn_mfma_f32_16x16x32_bf16(af[t], bf[u], acc[t][u], 0, 0, 0);
        }
    }

    float biasv[4];
    #pragma unroll
    for (int u = 0; u < 4; ++u) biasv[u] = bia[n0 + wc * 64 + u * 16 + arow];

    #pragma unroll
    for (int t = 0; t < 4; ++t) {
        #pragma unroll
        for (int u = 0; u < 4; ++u) {
            #pragma unroll
            for (int r = 0; r < 4; ++r) {
                int m = m0 + wr * 64 + t * 16 + 4 * ag + r;
                int n = n0 + wc * 64 + u * 16 + arow;
                int b = m >> 11, s = m & 2047;
                int hh = n >> 6, hd = n & 63;
                O[((((size_t)b * Hq + hh) * Sq + s) << 6) + hd] =
                    __float2bfloat16((acc[t][u][r] + biasv[u]) * sc);
            }
        }
    }
}

// ---------------- F^T = (K+V)^T per head, kappa-PERMUTED columns: Ftp[bh][d][st][p] ----------------
// position p = 32h + 8ag + j  holds  k = 16*(2*(j>>2)+h) + 4*ag + (j&3)   (bijection on 0..63)
__global__ __launch_bounds__(256)
void fuse_t_kernel(const __hip_bfloat16* __restrict__ Kh, const __hip_bfloat16* __restrict__ Vh,
                   __hip_bfloat16* __restrict__ Ft) {
    __shared__ float T[64][65];
    const int bh = blockIdx.x >> 5;
    const int st = blockIdx.x & 31;
    const int tid = threadIdx.x;

    #pragma unroll
    for (int p = 0; p < 2; ++p) {
        int idx = p * 256 + tid;
        int r = idx >> 3;
        int c = (idx & 7) * 8;
        size_t g = ((size_t)bh * Sq + st * 64 + r) * 64 + c;
        float4 k4 = *(const float4*)((const char*)Kh + g * 2);
        float4 v4 = *(const float4*)((const char*)Vh + g * 2);
        const __hip_bfloat16* kp = (const __hip_bfloat16*)&k4;
        const __hip_bfloat16* vp = (const __hip_bfloat16*)&v4;
        #pragma unroll
        for (int j = 0; j < 8; ++j)
            T[r][c + j] = __bfloat162float(kp[j]) + __bfloat162float(vp[j]);
    }
    __syncthreads();
    #pragma unroll
    for (int pp = 0; pp < 2; ++pp) {
        int idx = pp * 256 + tid;
        int d  = idx >> 3;
        int p8 = (idx & 7) * 8;
        alignas(16) __hip_bfloat16 tmp[8];
        #pragma unroll
        for (int j2 = 0; j2 < 8; ++j2) {
            int p = p8 + j2;
            int h  = p >> 5;
            int ag = (p >> 3) & 3;
            int j  = p & 7;
            int k  = 16 * (2 * (j >> 2) + h) + 4 * ag + (j & 3);
            tmp[j2] = __float2bfloat16(T[k][d]);
        }
        *(float4*)((char*)Ft + (((size_t)bh * 64 + d) * Sq + st * 64 + p8) * 2) = *(const float4*)tmp;
    }
}

// ---------------- MFMA attention: chunk-skewed pipeline (QK(c) || exp/PV(c-1)) ----------------
// K/V double-buffered in LDS via gload_lds; F and Q fragments direct from global (L1/L2-resident).
__global__ __launch_bounds__(256, 2)
void attn_kernel(const __hip_bfloat16* __restrict__ Qh, const __hip_bfloat16* __restrict__ Kh,
                 const __hip_bfloat16* __restrict__ Vh, const __hip_bfloat16* __restrict__ Ft,
                 float* __restrict__ part) {
    __shared__ alignas(16) short Ks[2][64 * 64];   // 2 x 8 KB
    __shared__ alignas(16) short Vs[2][64 * 64];
    __shared__ float part_s[8][64];                // 2 KB

    const int tid  = threadIdx.x;
    const int lane = tid & 63;
    const int w    = tid >> 6;                 // wave 0..3, owns q rows [w*32, w*32+32)
    // XCD-chunked swizzle: 512 blocks, each XCD owns 64 consecutive logical blocks (2 heads)
    const int lb   = (blockIdx.x & 7) * 64 + (blockIdx.x >> 3);
    const int bh   = lb >> 4;                  // 16 blocks per (b,h)
    const int s0   = (lb & 15) * 128;

    const char* Qbh = (const char*)(Qh + (size_t)bh * Sq * 64);
    const char* Kbh = (const char*)(Kh + (size_t)bh * Sq * 64);
    const char* Vbh = (const char*)(Vh + (size_t)bh * Sq * 64);
    const char* Fbh = (const char*)(Ft + (size_t)bh * 64 * Sq);

    const int arow = lane & 15;
    const int ag   = lane >> 4;

    // Q fragments (MFMA B operands after the swap) direct from global
    short8 qa[2][2];
    #pragma unroll
    for (int tile = 0; tile < 2; ++tile) {
        int qrg = s0 + w * 32 + tile * 16 + arow;
        qa[tile][0] = *(const short8*)(Qbh + ((size_t)qrg * 64 + 8 * ag) * 2);
        qa[tile][1] = *(const short8*)(Qbh + ((size_t)qrg * 64 + 32 + 8 * ag) * 2);
    }

    // all-ones bf16 A-fragment: mfma(ones, P) row m = sum_k P[k][q] (softmax denominator)
    short8 ones;
    #pragma unroll
    for (int j = 0; j < 8; ++j) ones[j] = (short)0x3F80;

    // acc_*[tile][td][r] = O^T[d = 16*td + 4*ag + r][q = w*32 + tile*16 + arow]
    f32x4 acc_k[2][4], acc_v[2][4];
    f32x4 acc_lk[2], acc_lv[2];
    #pragma unroll
    for (int tile = 0; tile < 2; ++tile) {
        #pragma unroll
        for (int t = 0; t < 4; ++t) {
            acc_k[tile][t] = (f32x4){0.f, 0.f, 0.f, 0.f};
            acc_v[tile][t] = (f32x4){0.f, 0.f, 0.f, 0.f};
        }
        acc_lk[tile] = (f32x4){0.f, 0.f, 0.f, 0.f};
        acc_lv[tile] = (f32x4){0.f, 0.f, 0.f, 0.f};
    }

    // K/V staging geometry (granule = 16B): 2 passes x 256 threads per array
    int sbyte[2];
    size_t kof[2];
    #pragma unroll
    for (int p = 0; p < 2; ++p) {
        int row = p * 32 + w * 8 + (lane >> 3);
        int scs = (lane & 7) ^ (row & 7);           // source pre-swizzle (involution)
        sbyte[p] = p * 4096 + w * 1024;             // wave-uniform linear LDS base
        kof[p] = ((size_t)row * 64 + scs * 8) * 2;
    }

    // F fragment base pointers (kappa-permuted Ft, direct global reads)
    const char* fbase[4];
    #pragma unroll
    for (int td = 0; td < 4; ++td)
        fbase[td] = Fbh + (size_t)(td * 16 + arow) * Sq * 2 + 16 * ag;

    f32x4 skA[2][4], svA[2][4], skB[2][4], svB[2][4];

#define STAGE(CN) do { if ((CN) < NCHUNK) {                                    \
    const size_t kv_ = (size_t)(CN) * 64;                                      \
    char* kb_ = (char*)Ks[(CN) & 1];                                           \
    char* vb_ = (char*)Vs[(CN) & 1];                                           \
    _Pragma("unroll")                                                          \
    for (int p_ = 0; p_ < 2; ++p_) {                                           \
        gload16(Kbh + kv_ * 128 + kof[p_], kb_ + sbyte[p_]);                   \
        gload16(Vbh + kv_ * 128 + kof[p_], vb_ + sbyte[p_]);                   \
    } } } while (0)

#define QKM(CK, SK, SV) do {                                                   \
    const char* kbase_ = (const char*)Ks[(CK) & 1];                            \
    const char* vbase_ = (const char*)Vs[(CK) & 1];                            \
    _Pragma("unroll")                                                          \
    for (int tl_ = 0; tl_ < 2; ++tl_)                                          \
        _Pragma("unroll")                                                      \
        for (int t_ = 0; t_ < 4; ++t_) {                                       \
            SK[tl_][t_] = (f32x4){0.f, 0.f, 0.f, 0.f};                         \
            SV[tl_][t_] = (f32x4){0.f, 0.f, 0.f, 0.f};                         \
        }                                                                      \
    __builtin_amdgcn_s_setprio(1);                                             \
    _Pragma("unroll")                                                          \
    for (int t_ = 0; t_ < 4; ++t_) {                                           \
        int brow_ = t_ * 16 + arow;                                            \
        int bswz_ = (brow_ & 7) << 4;                                          \
        short8 kb0_ = *(const short8*)(kbase_ + brow_ * 128 + ((16 * ag) ^ bswz_));        \
        short8 kb1_ = *(const short8*)(kbase_ + brow_ * 128 + ((64 + 16 * ag) ^ bswz_));   \
        short8 vb0_ = *(const short8*)(vbase_ + brow_ * 128 + ((16 * ag) ^ bswz_));        \
        short8 vb1_ = *(const short8*)(vbase_ + brow_ * 128 + ((64 + 16 * ag) ^ bswz_));   \
        _Pragma("unroll")                                                      \
        for (int tl_ = 0; tl_ < 2; ++tl_) {                                    \
            SK[tl_][t_] = __builtin_amdgcn_mfma_f32_16x16x32_bf16(kb0_, qa[tl_][0], SK[tl_][t_], 0, 0, 0); \
            SK[tl_][t_] = __builtin_amdgcn_mfma_f32_16x16x32_bf16(kb1_, qa[tl_][1], SK[tl_][t_], 0, 0, 0); \
            SV[tl_][t_] = __builtin_amdgcn_mfma_f32_16x16x32_bf16(vb0_, qa[tl_][0], SV[tl_][t_], 0, 0, 0); \
            SV[tl_][t_] = __builtin_amdgcn_mfma_f32_16x16x32_bf16(vb1_, qa[tl_][1], SV[tl_][t_], 0, 0, 0); \
        }                                                                      \
    }                                                                          \
    __builtin_amdgcn_s_setprio(0);                                             \
} while (0)

#define EXPPV(CKP, SK, SV) do {                                                \
    short8 bpk_[2][2], bpv_[2][2];                                             \
    _Pragma("unroll")                                                          \
    for (int tl_ = 0; tl_ < 2; ++tl_)                                          \
        _Pragma("unroll")                                                      \
        for (int t_ = 0; t_ < 4; ++t_)                                         \
            _Pragma("unroll")                                                  \
            for (int r_ = 0; r_ < 4; ++r_) {                                   \
                bpk_[tl_][t_ & 1][4 * (t_ >> 1) + r_] = bfs(EXP2(SK[tl_][t_][r_])); \
                bpv_[tl_][t_ & 1][4 * (t_ >> 1) + r_] = bfs(EXP2(SV[tl_][t_][r_])); \
            }                                                                  \
    const size_t fco_ = (size_t)(CKP) * 128;                                   \
    __builtin_amdgcn_s_setprio(1);                                             \
    _Pragma("unroll")                                                          \
    for (int td_ = 0; td_ < 4; ++td_) {                                        \
        short8 fa0_ = *(const short8*)(fbase[td_] + fco_);                     \
        short8 fa1_ = *(const short8*)(fbase[td_] + fco_ + 64);                \
        _Pragma("unroll")                                                      \
        for (int tl_ = 0; tl_ < 2; ++tl_) {                                    \
            acc_k[tl_][td_] = __builtin_amdgcn_mfma_f32_16x16x32_bf16(fa0_, bpk_[tl_][0], acc_k[tl_][td_], 0, 0, 0); \
            acc_k[tl_][td_] = __builtin_amdgcn_mfma_f32_16x16x32_bf16(fa1_, bpk_[tl_][1], acc_k[tl_][td_], 0, 0, 0); \
            acc_v[tl_][td_] = __builtin_amdgcn_mfma_f32_16x16x32_bf16(fa0_, bpv_[tl_][0], acc_v[tl_][td_], 0, 0, 0); \
            acc_v[tl_][td_] = __builtin_amdgcn_mfma_f32_16x16x32_bf16(fa1_, bpv_[tl_][1], acc_v[tl_][td_], 0, 0, 0); \
        }                                                                      \
    }                                                                          \
    _Pragma("unroll")                                                          \
    for (int tl_ = 0; tl_ < 2; ++tl_) {                                        \
        acc_lk[tl_] = __builtin_amdgcn_mfma_f32_16x16x32_bf16(ones, bpk_[tl_][0], acc_lk[tl_], 0, 0, 0); \
        acc_lk[tl_] = __builtin_amdgcn_mfma_f32_16x16x32_bf16(ones, bpk_[tl_][1], acc_lk[tl_], 0, 0, 0); \
        acc_lv[tl_] = __builtin_amdgcn_mfma_f32_16x16x32_bf16(ones, bpv_[tl_][0], acc_lv[tl_], 0, 0, 0); \
        acc_lv[tl_] = __builtin_amdgcn_mfma_f32_16x16x32_bf16(ones, bpv_[tl_][1], acc_lv[tl_], 0, 0, 0); \
    }                                                                          \
    __builtin_amdgcn_s_setprio(0);                                             \
} while (0)

    // ---- skewed pipeline: QK(c) overlaps exp/PV(c-1) ----
    STAGE(0);
    __syncthreads();           // chunk 0 landed
    STAGE(1);
    QKM(0, skA, svA);
    for (int c = 1; c < NCHUNK - 1; c += 2) {
        __syncthreads();       // drains STAGE(c); QK(c-1) readers done
        STAGE(c + 1);
        QKM(c, skB, svB);
        EXPPV(c - 1, skA, svA);
        __syncthreads();
        STAGE(c + 2);
        QKM(c + 1, skA, svA);
        EXPPV(c, skB, svB);
    }
    __syncthreads();
    QKM(NCHUNK - 1, skB, svB);
    EXPPV(NCHUNK - 2, skA, svA);
    EXPPV(NCHUNK - 1, skB, svB);

#undef STAGE
#undef QKM
#undef EXPPV

    // ---- epilogue (per q-tile): denominators complete per-lane via ones-MFMA ----
    #pragma unroll
    for (int tile = 0; tile < 2; ++tile) {
        float ilk = INV_SCALE2 / acc_lk[tile][0];
        float ilv = INV_SCALE2 / acc_lv[tile][0];

        int qrg = s0 + w * 32 + tile * 16 + arow;
        f32x4 c[4];
        #pragma unroll
        for (int td = 0; td < 4; ++td) {
            #pragma unroll
            for (int r = 0; r < 4; ++r) {
                int d = 16 * td + 4 * ag + r;
                float qv = __bfloat162float(*(const __hip_bfloat16*)(
                    Qbh + ((size_t)qrg * 64 + d) * 2));
                c[td][r] = (acc_k[tile][td][r] * ilk + acc_v[tile][td][r] * ilv) * qv;
            }
        }
        #pragma unroll
        for (int off = 1; off < 16; off <<= 1) {
            #pragma unroll
            for (int td = 0; td < 4; ++td) {
                #pragma unroll
                for (int r = 0; r < 4; ++r) c[td][r] += __shfl_xor(c[td][r], off);
            }
        }
        if (arow == 0) {
            #pragma unroll
            for (int td = 0; td < 4; ++td)
                #pragma unroll
                for (int r = 0; r < 4; ++r)
                    part_s[w * 2 + tile][16 * td + 4 * ag + r] = c[td][r];
        }
    }
    __syncthreads();
    if (tid < 64) {
        float t = 0.f;
        #pragma unroll
        for (int r = 0; r < 8; ++r) t += part_s[r][tid];
        part[(size_t)lb * 64 + tid] = t;
    }
}

// ---------------- deterministic final reduction ----------------
__global__ void reduce_kernel(const float* __restrict__ part, float* __restrict__ out) {
    int bh = blockIdx.x;     // 0..31
    int d  = threadIdx.x;    // 0..63
    float t = 0.f;
    for (int i = 0; i < 16; ++i)
        t += part[(size_t)(bh * 16 + i) * 64 + d];
    out[bh * 64 + d] = t;
}

extern "C" void kernel_launch(void* const* d_in, const int* in_sizes, int n_in,
                              void* d_out, int out_size, void* d_ws, size_t ws_size,
                              hipStream_t stream) {
    const float* value = (const float*)d_in[0];
    const float* key   = (const float*)d_in[1];
    const float* query = (const float*)d_in[2];
    const float* Wv    = (const float*)d_in[3];
    const float* bv    = (const float*)d_in[4];
    const float* Wk    = (const float*)d_in[5];
    const float* bk    = (const float*)d_in[6];
    const float* Wq    = (const float*)d_in[7];
    const float* bq    = (const float*)d_in[8];
    float* out = (float*)d_out;

    char* w = (char*)d_ws;
    __hip_bfloat16* Qh = (__hip_bfloat16*)(w);
    __hip_bfloat16* Kh = (__hip_bfloat16*)(w + (size_t)8  * 1024 * 1024);
    __hip_bfloat16* Vh = (__hip_bfloat16*)(w + (size_t)16 * 1024 * 1024);
    __hip_bfloat16* Ft = (__hip_bfloat16*)(w + (size_t)24 * 1024 * 1024);
    float*          part = (float*)      (w + (size_t)32 * 1024 * 1024);

    dim3 pg(Dq / 128, (Bq * Sq) / 128, 3);  // (4, 64, 3)
    proj_kernel<<<pg, 256, 0, stream>>>(value, key, query, Wv, Wk, Wq, bv, bk, bq, Vh, Kh, Qh);

    fuse_t_kernel<<<1024, 256, 0, stream>>>(Kh, Vh, Ft);
    attn_kernel<<<512, 256, 0, stream>>>(Qh, Kh, Vh, Ft, part);
    reduce_kernel<<<32, 64, 0, stream>>>(part, out);
}

// Round 16
// 120.479 us; speedup vs baseline: 1.7599x; 1.7599x over previous
//
#include <hip/hip_runtime.h>
#include <hip/hip_bf16.h>

#define Bq 4
#define Sq 2048
#define Dq 512
#define Hq 8
#define HDq 64

typedef __attribute__((ext_vector_type(8))) short short8;
typedef __attribute__((ext_vector_type(4))) float f32x4;

#if __has_builtin(__builtin_amdgcn_exp2f)
#define EXP2(x) __builtin_amdgcn_exp2f(x)
#else
#define EXP2(x) exp2f(x)
#endif

// softmax scale folded into Q projection: q_stored = q * 0.125 * log2(e)
#define SCALE2 (0.125f * 1.44269504088896340736f)
#define INV_SCALE2 (5.545177444479562f)

__device__ __forceinline__ short bfs(float x) {
    __hip_bfloat16 h = __float2bfloat16(x);
    short r;
    __builtin_memcpy(&r, &h, 2);
    return r;
}

__device__ __forceinline__ short8 cvt8(float4 a, float4 b) {
    union { __hip_bfloat16 h[8]; short8 s; } u;
    u.h[0] = __float2bfloat16(a.x); u.h[1] = __float2bfloat16(a.y);
    u.h[2] = __float2bfloat16(a.z); u.h[3] = __float2bfloat16(a.w);
    u.h[4] = __float2bfloat16(b.x); u.h[5] = __float2bfloat16(b.y);
    u.h[6] = __float2bfloat16(b.z); u.h[7] = __float2bfloat16(b.w);
    return u.s;
}

// direct global->LDS async copy, 16B per lane (LDS dest = wave-uniform base + lane*16)
__device__ __forceinline__ void gload16(const void* g, void* l) {
    __builtin_amdgcn_global_load_lds(
        (const __attribute__((address_space(1))) unsigned int*)g,
        (__attribute__((address_space(3))) unsigned int*)l, 16, 0, 0);
}

// ---------------- batched MFMA projection: O = (X @ W^T + bias) * sc, bf16 head layout ----------------
__global__ __launch_bounds__(256, 3)
void proj_kernel(const float* __restrict__ Xv, const float* __restrict__ Xk, const float* __restrict__ Xq,
                 const float* __restrict__ Wv, const float* __restrict__ Wk, const float* __restrict__ Wq,
                 const float* __restrict__ bv, const float* __restrict__ bk, const float* __restrict__ bq,
                 __hip_bfloat16* __restrict__ Ov, __hip_bfloat16* __restrict__ Ok, __hip_bfloat16* __restrict__ Oq) {
    __shared__ alignas(16) short As[128 * 64];
    __shared__ alignas(16) short Bs[128 * 64];

    const int z = blockIdx.z;
    const float* X   = (z == 0) ? Xv : (z == 1) ? Xk : Xq;
    const float* W   = (z == 0) ? Wv : (z == 1) ? Wk : Wq;
    const float* bia = (z == 0) ? bv : (z == 1) ? bk : bq;
    __hip_bfloat16* O = (z == 0) ? Ov : (z == 1) ? Ok : Oq;
    const float sc = (z == 2) ? SCALE2 : 1.0f;

    const int tid  = threadIdx.x;
    const int lane = tid & 63;
    const int w    = tid >> 6;
    const int wr   = w >> 1;
    const int wc   = w & 1;
    const int m0   = blockIdx.y * 128;
    const int n0   = blockIdx.x * 128;
    const int arow = lane & 15;
    const int ag   = lane >> 4;

    f32x4 acc[4][4];
    #pragma unroll
    for (int t = 0; t < 4; ++t)
        #pragma unroll
        for (int u = 0; u < 4; ++u) acc[t][u] = (f32x4){0.f, 0.f, 0.f, 0.f};

    for (int kk = 0; kk < Dq / 64; ++kk) {
        __syncthreads();
        #pragma unroll
        for (int p = 0; p < 4; ++p) {
            int id  = p * 256 + tid;
            int row = id >> 3;
            int c   = id & 7;
            int dst = row * 128 + ((c * 16) ^ ((row & 7) << 4));
            const float* ax = X + (size_t)(m0 + row) * Dq + kk * 64 + c * 8;
            const float* bx = W + (size_t)(n0 + row) * Dq + kk * 64 + c * 8;
            float4 a0 = *(const float4*)ax;
            float4 a1 = *(const float4*)(ax + 4);
            float4 b0 = *(const float4*)bx;
            float4 b1 = *(const float4*)(bx + 4);
            *(short8*)((char*)As + dst) = cvt8(a0, a1);
            *(short8*)((char*)Bs + dst) = cvt8(b0, b1);
        }
        __syncthreads();
        #pragma unroll
        for (int h = 0; h < 2; ++h) {
            short8 af[4], bf[4];
            #pragma unroll
            for (int t = 0; t < 4; ++t) {
                int ra = wr * 64 + t * 16 + arow;
                int rb = wc * 64 + t * 16 + arow;
                af[t] = *(const short8*)((const char*)As + ra * 128 + ((h * 64 + ag * 16) ^ ((ra & 7) << 4)));
                bf[t] = *(const short8*)((const char*)Bs + rb * 128 + ((h * 64 + ag * 16) ^ ((rb & 7) << 4)));
            }
            #pragma unroll
            for (int t = 0; t < 4; ++t)
                #pragma unroll
                for (int u = 0; u < 4; ++u)
                    acc[t][u] = __builtin_amdgcn_mfma_f32_16x16x32_bf16(af[t], bf[u], acc[t][u], 0, 0, 0);
        }
    }

    float biasv[4];
    #pragma unroll
    for (int u = 0; u < 4; ++u) biasv[u] = bia[n0 + wc * 64 + u * 16 + arow];

    #pragma unroll
    for (int t = 0; t < 4; ++t) {
        #pragma unroll
        for (int u = 0; u < 4; ++u) {
            #pragma unroll
            for (int r = 0; r < 4; ++r) {
                int m = m0 + wr * 64 + t * 16 + 4 * ag + r;
                int n = n0 + wc * 64 + u * 16 + arow;
                int b = m >> 11, s = m & 2047;
                int hh = n >> 6, hd = n & 63;
                O[((((size_t)b * Hq + hh) * Sq + s) << 6) + hd] =
                    __float2bfloat16((acc[t][u][r] + biasv[u]) * sc);
            }
        }
    }
}

// ---------------- F^T = (K+V)^T per head, kappa-PERMUTED columns: Ftp[bh][d][st][p] ----------------
// position p = 32h + 8ag + j  holds  k = 16*(2*(j>>2)+h) + 4*ag + (j&3)   (bijection on 0..63)
__global__ __launch_bounds__(256)
void fuse_t_kernel(const __hip_bfloat16* __restrict__ Kh, const __hip_bfloat16* __restrict__ Vh,
                   __hip_bfloat16* __restrict__ Ft) {
    __shared__ float T[64][65];
    const int bh = blockIdx.x >> 5;
    const int st = blockIdx.x & 31;
    const int tid = threadIdx.x;

    #pragma unroll
    for (int p = 0; p < 2; ++p) {
        int idx = p * 256 + tid;
        int r = idx >> 3;
        int c = (idx & 7) * 8;
        size_t g = ((size_t)bh * Sq + st * 64 + r) * 64 + c;
        float4 k4 = *(const float4*)((const char*)Kh + g * 2);
        float4 v4 = *(const float4*)((const char*)Vh + g * 2);
        const __hip_bfloat16* kp = (const __hip_bfloat16*)&k4;
        const __hip_bfloat16* vp = (const __hip_bfloat16*)&v4;
        #pragma unroll
        for (int j = 0; j < 8; ++j)
            T[r][c + j] = __bfloat162float(kp[j]) + __bfloat162float(vp[j]);
    }
    __syncthreads();
    #pragma unroll
    for (int pp = 0; pp < 2; ++pp) {
        int idx = pp * 256 + tid;
        int d  = idx >> 3;
        int p8 = (idx & 7) * 8;
        alignas(16) __hip_bfloat16 tmp[8];
        #pragma unroll
        for (int j2 = 0; j2 < 8; ++j2) {
            int p = p8 + j2;
            int h  = p >> 5;
            int ag = (p >> 3) & 3;
            int j  = p & 7;
            int k  = 16 * (2 * (j >> 2) + h) + 4 * ag + (j & 3);
            tmp[j2] = __float2bfloat16(T[k][d]);
        }
        *(float4*)((char*)Ft + (((size_t)bh * 64 + d) * Sq + st * 64 + p8) * 2) = *(const float4*)tmp;
    }
}

// ---------------- MFMA attention: 2 q-tiles/wave, lp via ones-MFMA, setprio ----------------
__global__ __launch_bounds__(256, 2)
void attn_kernel(const __hip_bfloat16* __restrict__ Qh, const __hip_bfloat16* __restrict__ Kh,
                 const __hip_bfloat16* __restrict__ Vh, const __hip_bfloat16* __restrict__ Ft,
                 float* __restrict__ part) {
    __shared__ alignas(16) short Qs[128 * 64];   // 16 KB
    __shared__ alignas(16) short Ks[64 * 64];    // 8 KB (aliased as epilogue scratch)
    __shared__ alignas(16) short Vs[64 * 64];
    __shared__ alignas(16) short Fs[64 * 64];

    const int tid  = threadIdx.x;
    const int lane = tid & 63;
    const int w    = tid >> 6;                 // wave 0..3, owns q rows [w*32, w*32+32)
    // XCD-chunked swizzle: 512 blocks, each XCD owns 64 consecutive logical blocks (2 heads)
    const int lb   = (blockIdx.x & 7) * 64 + (blockIdx.x >> 3);
    const int bh   = lb >> 4;                  // 16 blocks per (b,h)
    const int s0   = (lb & 15) * 128;

    const char* Qbh = (const char*)(Qh + (size_t)bh * Sq * 64);
    const char* Kbh = (const char*)(Kh + (size_t)bh * Sq * 64);
    const char* Vbh = (const char*)(Vh + (size_t)bh * Sq * 64);
    const char* Fbh = (const char*)(Ft + (size_t)bh * 64 * Sq);

    // stage Q tile (128 rows x 64 dims, swizzled)
    #pragma unroll
    for (int p = 0; p < 4; ++p) {
        int idx = p * 256 + tid;
        int r = idx >> 3;
        int c = idx & 7;
        int swz = (r & 7) << 4;
        float4 q4 = *(const float4*)(Qbh + ((size_t)(s0 + r) * 64 + c * 8) * 2);
        *(float4*)((char*)Qs + r * 128 + ((c * 16) ^ swz)) = q4;
    }
    __syncthreads();

    const int arow = lane & 15;
    const int ag   = lane >> 4;

    // Q fragments for both q-tiles (MFMA B operands after the swap)
    short8 qa[2][2];
    #pragma unroll
    for (int tile = 0; tile < 2; ++tile) {
        int qr = w * 32 + tile * 16 + arow;
        int qswz = (qr & 7) << 4;
        qa[tile][0] = *(const short8*)((const char*)Qs + qr * 128 + ((16 * ag) ^ qswz));
        qa[tile][1] = *(const short8*)((const char*)Qs + qr * 128 + ((64 + 16 * ag) ^ qswz));
    }

    // all-ones bf16 A-fragment: mfma(ones, P) row m = sum_k P[k][q] (softmax denominator)
    short8 ones;
    #pragma unroll
    for (int j = 0; j < 8; ++j) ones[j] = (short)0x3F80;

    // acc_*[tile][td][r] = O^T[d = 16*td + 4*ag + r][q = w*32 + tile*16 + arow]
    f32x4 acc_k[2][4], acc_v[2][4];
    f32x4 acc_lk[2], acc_lv[2];     // denominator accumulators (all rows identical)
    #pragma unroll
    for (int tile = 0; tile < 2; ++tile) {
        #pragma unroll
        for (int t = 0; t < 4; ++t) {
            acc_k[tile][t] = (f32x4){0.f, 0.f, 0.f, 0.f};
            acc_v[tile][t] = (f32x4){0.f, 0.f, 0.f, 0.f};
        }
        acc_lk[tile] = (f32x4){0.f, 0.f, 0.f, 0.f};
        acc_lv[tile] = (f32x4){0.f, 0.f, 0.f, 0.f};
    }

    // staging geometry (granule = 16B): per chunk each wave stages 2x1024B per array.
    int srow[2], sbyte[2];
    size_t kof[2], fof[2];
    #pragma unroll
    for (int p = 0; p < 2; ++p) {
        srow[p] = p * 32 + w * 8 + (lane >> 3);
        int scs = (lane & 7) ^ (srow[p] & 7);
        sbyte[p] = p * 4096 + w * 1024;
        kof[p] = ((size_t)srow[p] * 64 + scs * 8) * 2;
        fof[p] = ((size_t)srow[p] * Sq + scs * 8) * 2;
    }

    for (int ck = 0; ck < Sq / 64; ++ck) {
        const size_t kv0 = (size_t)ck * 64;
        __syncthreads();   // prior chunk's LDS readers done
        #pragma unroll
        for (int p = 0; p < 2; ++p) {
            gload16(Kbh + kv0 * 128 + kof[p], (char*)Ks + sbyte[p]);
            gload16(Vbh + kv0 * 128 + kof[p], (char*)Vs + sbyte[p]);
            gload16(Fbh + fof[p] + kv0 * 2,   (char*)Fs + sbyte[p]);
        }
        __syncthreads();   // barrier drains vmcnt -> staged data visible

        // ---- swapped scores: S^T = mfma(K_frag, Q_frag); each K/V frag feeds both q-tiles ----
        f32x4 sk[2][4], sv[2][4];
        #pragma unroll
        for (int tile = 0; tile < 2; ++tile)
            #pragma unroll
            for (int t = 0; t < 4; ++t) {
                sk[tile][t] = (f32x4){0.f, 0.f, 0.f, 0.f};
                sv[tile][t] = (f32x4){0.f, 0.f, 0.f, 0.f};
            }
        __builtin_amdgcn_s_setprio(1);
        #pragma unroll
        for (int t = 0; t < 4; ++t) {
            int brow = t * 16 + arow;
            int bswz = (brow & 7) << 4;
            short8 kb0 = *(const short8*)((const char*)Ks + brow * 128 + ((16 * ag) ^ bswz));
            short8 kb1 = *(const short8*)((const char*)Ks + brow * 128 + ((64 + 16 * ag) ^ bswz));
            short8 vb0 = *(const short8*)((const char*)Vs + brow * 128 + ((16 * ag) ^ bswz));
            short8 vb1 = *(const short8*)((const char*)Vs + brow * 128 + ((64 + 16 * ag) ^ bswz));
            #pragma unroll
            for (int tile = 0; tile < 2; ++tile) {
                sk[tile][t] = __builtin_amdgcn_mfma_f32_16x16x32_bf16(kb0, qa[tile][0], sk[tile][t], 0, 0, 0);
                sk[tile][t] = __builtin_amdgcn_mfma_f32_16x16x32_bf16(kb1, qa[tile][1], sk[tile][t], 0, 0, 0);
                sv[tile][t] = __builtin_amdgcn_mfma_f32_16x16x32_bf16(vb0, qa[tile][0], sv[tile][t], 0, 0, 0);
                sv[tile][t] = __builtin_amdgcn_mfma_f32_16x16x32_bf16(vb1, qa[tile][1], sv[tile][t], 0, 0, 0);
            }
        }
        __builtin_amdgcn_s_setprio(0);

        // ---- static softmax per tile, exp2 -> bf16 straight into B-frag slots ----
        short8 bpk[2][2], bpv[2][2];
        #pragma unroll
        for (int tile = 0; tile < 2; ++tile) {
            #pragma unroll
            for (int t = 0; t < 4; ++t) {
                #pragma unroll
                for (int r = 0; r < 4; ++r) {
                    bpk[tile][t & 1][4 * (t >> 1) + r] = bfs(EXP2(sk[tile][t][r]));
                    bpv[tile][t & 1][4 * (t >> 1) + r] = bfs(EXP2(sv[tile][t][r]));
                }
            }
        }

        // ---- PV^T + denominator MFMAs ----
        __builtin_amdgcn_s_setprio(1);
        #pragma unroll
        for (int td = 0; td < 4; ++td) {
            int row = td * 16 + arow;
            int rswz = (row & 7) << 4;
            short8 fa0 = *(const short8*)((const char*)Fs + row * 128 + ((16 * ag) ^ rswz));
            short8 fa1 = *(const short8*)((const char*)Fs + row * 128 + ((64 + 16 * ag) ^ rswz));
            #pragma unroll
            for (int tile = 0; tile < 2; ++tile) {
                acc_k[tile][td] = __builtin_amdgcn_mfma_f32_16x16x32_bf16(fa0, bpk[tile][0], acc_k[tile][td], 0, 0, 0);
                acc_k[tile][td] = __builtin_amdgcn_mfma_f32_16x16x32_bf16(fa1, bpk[tile][1], acc_k[tile][td], 0, 0, 0);
                acc_v[tile][td] = __builtin_amdgcn_mfma_f32_16x16x32_bf16(fa0, bpv[tile][0], acc_v[tile][td], 0, 0, 0);
                acc_v[tile][td] = __builtin_amdgcn_mfma_f32_16x16x32_bf16(fa1, bpv[tile][1], acc_v[tile][td], 0, 0, 0);
            }
        }
        #pragma unroll
        for (int tile = 0; tile < 2; ++tile) {
            acc_lk[tile] = __builtin_amdgcn_mfma_f32_16x16x32_bf16(ones, bpk[tile][0], acc_lk[tile], 0, 0, 0);
            acc_lk[tile] = __builtin_amdgcn_mfma_f32_16x16x32_bf16(ones, bpk[tile][1], acc_lk[tile], 0, 0, 0);
            acc_lv[tile] = __builtin_amdgcn_mfma_f32_16x16x32_bf16(ones, bpv[tile][0], acc_lv[tile], 0, 0, 0);
            acc_lv[tile] = __builtin_amdgcn_mfma_f32_16x16x32_bf16(ones, bpv[tile][1], acc_lv[tile], 0, 0, 0);
        }
        __builtin_amdgcn_s_setprio(0);
    }

    // ---- epilogue (per q-tile): denominators already complete per-lane ----
    __syncthreads();               // all waves done with Ks -> reuse as scratch
    float* part_s = (float*)Ks;    // [8][64]: row = w*2 + tile
    #pragma unroll
    for (int tile = 0; tile < 2; ++tile) {
        float ilk = INV_SCALE2 / acc_lk[tile][0];
        float ilv = INV_SCALE2 / acc_lv[tile][0];

        int qr = w * 32 + tile * 16 + arow;
        f32x4 c[4];
        #pragma unroll
        for (int td = 0; td < 4; ++td) {
            #pragma unroll
            for (int r = 0; r < 4; ++r) {
                int d = 16 * td + 4 * ag + r;
                int byte = 2 * d;
                float qv = __bfloat162float(*(const __hip_bfloat16*)(
                    (const char*)Qs + qr * 128 + (((byte & ~15) ^ ((qr & 7) << 4)) | (byte & 15))));
                c[td][r] = (acc_k[tile][td][r] * ilk + acc_v[tile][td][r] * ilv) * qv;
            }
        }
        #pragma unroll
        for (int off = 1; off < 16; off <<= 1) {
            #pragma unroll
            for (int td = 0; td < 4; ++td) {
                #pragma unroll
                for (int r = 0; r < 4; ++r) c[td][r] += __shfl_xor(c[td][r], off);
            }
        }
        if (arow == 0) {
            #pragma unroll
            for (int td = 0; td < 4; ++td)
                #pragma unroll
                for (int r = 0; r < 4; ++r)
                    part_s[(w * 2 + tile) * 64 + 16 * td + 4 * ag + r] = c[td][r];
        }
    }
    __syncthreads();
    if (tid < 64) {
        float t = 0.f;
        #pragma unroll
        for (int r = 0; r < 8; ++r) t += part_s[r * 64 + tid];
        part[(size_t)lb * 64 + tid] = t;
    }
}

// ---------------- deterministic final reduction ----------------
__global__ void reduce_kernel(const float* __restrict__ part, float* __restrict__ out) {
    int bh = blockIdx.x;     // 0..31
    int d  = threadIdx.x;    // 0..63
    float t = 0.f;
    for (int i = 0; i < 16; ++i)
        t += part[(size_t)(bh * 16 + i) * 64 + d];
    out[bh * 64 + d] = t;
}

extern "C" void kernel_launch(void* const* d_in, const int* in_sizes, int n_in,
                              void* d_out, int out_size, void* d_ws, size_t ws_size,
                              hipStream_t stream) {
    const float* value = (const float*)d_in[0];
    const float* key   = (const float*)d_in[1];
    const float* query = (const float*)d_in[2];
    const float* Wv    = (const float*)d_in[3];
    const float* bv    = (const float*)d_in[4];
    const float* Wk    = (const float*)d_in[5];
    const float* bk    = (const float*)d_in[6];
    const float* Wq    = (const float*)d_in[7];
    const float* bq    = (const float*)d_in[8];
    float* out = (float*)d_out;

    char* w = (char*)d_ws;
    __hip_bfloat16* Qh = (__hip_bfloat16*)(w);
    __hip_bfloat16* Kh = (__hip_bfloat16*)(w + (size_t)8  * 1024 * 1024);
    __hip_bfloat16* Vh = (__hip_bfloat16*)(w + (size_t)16 * 1024 * 1024);
    __hip_bfloat16* Ft = (__hip_bfloat16*)(w + (size_t)24 * 1024 * 1024);
    float*          part = (float*)      (w + (size_t)32 * 1024 * 1024);

    dim3 pg(Dq / 128, (Bq * Sq) / 128, 3);  // (4, 64, 3)
    proj_kernel<<<pg, 256, 0, stream>>>(value, key, query, Wv, Wk, Wq, bv, bk, bq, Vh, Kh, Qh);

    fuse_t_kernel<<<1024, 256, 0, stream>>>(Kh, Vh, Ft);
    attn_kernel<<<512, 256, 0, stream>>>(Qh, Kh, Vh, Ft, part);
    reduce_kernel<<<32, 64, 0, stream>>>(part, out);
}